// Round 3
// baseline (136.849 us; speedup 1.0000x reference)
//
#include <hip/hip_runtime.h>

// B=4, Sx=Sy=512, H=128, D=2H=256, fp32.
// e1 = exp2(2*log2e * x@W1^T), e2 = exp2(2*log2e * y@W2^T)   (proj_kernel)
// tanh(s1+s2) = 1 - 2/(e1*e2 + 1); score = sum_h vc[h]*tanh(...)
// (constant sum_h vc[h] dropped: softmax shift-invariant)
// P = softmax_s(score); out = P @ x                           (attn_kernel)
// Quad-rcp: a1/f1+a2/f2+a3/f3+a4/f4 = (n12*f34 + n34*f12)/(f12*f34).

#define NB 4
#define SEQ 512
#define HDIM 128
#define DDIM 256

static constexpr float TWO_LOG2E = 2.8853900817779268f; // 2*log2(e)
static constexpr float LOG2E     = 1.4426950408889634f;

// ---------------- Kernel A: projections + exp2 epilogue --------------------
// 512 blocks x 256 thr; block = 8 rows (x rows for blk<256 else y rows).
// Thread = (h-quad q in 0..31, k-eighth kh in 0..7): 4h x 8r x 32k register
// block. A (8x256) in LDS (broadcast reads); W from global/L2, each element
// read exactly once per block. One barrier before the k-split combine.
__global__ __launch_bounds__(256) void proj_kernel(
    const float* __restrict__ x, const float* __restrict__ y,
    const float* __restrict__ W1, const float* __restrict__ W2,
    float* __restrict__ e1out, float* __restrict__ e2out)
{
    __shared__ float As[2048];   // [8 r][256 k]
    __shared__ float sP[8192];   // [8 kh][8 r][128 h]
    const int tid = threadIdx.x;
    const int blk = blockIdx.x;

    const float* in; const float* W; float* outp; int rbase;
    if (blk < 256) { in = x; W = W1; outp = e1out; rbase = blk * 8; }
    else           { in = y; W = W2; outp = e2out; rbase = (blk - 256) * 8; }

    *(float4*)&As[tid*8]     = *(const float4*)&in[rbase*256 + tid*8];
    *(float4*)&As[tid*8 + 4] = *(const float4*)&in[rbase*256 + tid*8 + 4];
    __syncthreads();

    const int q  = tid & 31;   // h = 4q..4q+3
    const int kh = tid >> 5;   // k-range [32*kh, 32*kh+32)
    const int k0 = kh * 32;

    float4 acc4[8];
    #pragma unroll
    for (int r = 0; r < 8; ++r) acc4[r] = make_float4(0.f,0.f,0.f,0.f);

    #pragma unroll 2
    for (int kk = 0; kk < 32; kk += 4) {
        const float4 b0 = *(const float4*)&W[(4*q+0)*256 + k0 + kk];
        const float4 b1 = *(const float4*)&W[(4*q+1)*256 + k0 + kk];
        const float4 b2 = *(const float4*)&W[(4*q+2)*256 + k0 + kk];
        const float4 b3 = *(const float4*)&W[(4*q+3)*256 + k0 + kk];
        #pragma unroll
        for (int r = 0; r < 8; ++r) {
            const float4 a = *(const float4*)&As[r*256 + k0 + kk];
            acc4[r].x = fmaf(a.w,b0.w, fmaf(a.z,b0.z, fmaf(a.y,b0.y, fmaf(a.x,b0.x, acc4[r].x))));
            acc4[r].y = fmaf(a.w,b1.w, fmaf(a.z,b1.z, fmaf(a.y,b1.y, fmaf(a.x,b1.x, acc4[r].y))));
            acc4[r].z = fmaf(a.w,b2.w, fmaf(a.z,b2.z, fmaf(a.y,b2.y, fmaf(a.x,b2.x, acc4[r].z))));
            acc4[r].w = fmaf(a.w,b3.w, fmaf(a.z,b3.z, fmaf(a.y,b3.y, fmaf(a.x,b3.x, acc4[r].w))));
        }
    }
    #pragma unroll
    for (int r = 0; r < 8; ++r)
        *(float4*)&sP[kh*1024 + r*128 + q*4] = acc4[r];
    __syncthreads();

    const int r  = tid >> 5, h4 = tid & 31;
    float4 s = make_float4(0.f,0.f,0.f,0.f);
    #pragma unroll
    for (int k2 = 0; k2 < 8; ++k2) {
        const float4 p = *(const float4*)&sP[k2*1024 + r*128 + h4*4];
        s.x += p.x; s.y += p.y; s.z += p.z; s.w += p.w;
    }
    float4 o;
    o.x = __builtin_amdgcn_exp2f(s.x * TWO_LOG2E);
    o.y = __builtin_amdgcn_exp2f(s.y * TWO_LOG2E);
    o.z = __builtin_amdgcn_exp2f(s.z * TWO_LOG2E);
    o.w = __builtin_amdgcn_exp2f(s.w * TWO_LOG2E);
    *(float4*)&outp[(rbase + r)*128 + h4*4] = o;
}

// ---------------- Kernel B: fused scores + softmax + P@x -------------------
// 512 blocks x 512 thr (8 waves). Block = (b, 4 t rows). Wave w owns h-quads
// 4w..4w+3 (16 h) for ALL 4 t; e2/vc live in registers, hoisted over chunks.
// e1 staged 64-s chunks, XOR-swizzled float4 granules (conflict-free both
// directions). Per-chunk partials reduced across waves in LDS. P@x: wave
// (dq=w&3, sh=w>>2) serves all 4 t per x read; sh-halves combined in LDS.
__global__ __launch_bounds__(512, 4) void attn_kernel(
    const float* __restrict__ e1g, const float* __restrict__ e2g,
    const float* __restrict__ vc,  const float* __restrict__ x,
    float* __restrict__ out)
{
    __shared__ float regionA[16384];  // 64 KB
    __shared__ float regionB[2048];   // 8 KB
    float4* sE1q   = (float4*)regionA;          // [32 hq][64 s] swizzled
    float*  sScore = regionA + 8192;            // [4 t][512 s]
    float*  sPartC = regionA + 8192 + 2048;     // [8 w][4 t][64 s]
    float*  Xs     = regionA;                   // P@x: [64 s][256 d]
    float*  sPn    = regionB;                   // [512 s][4 t]
    float*  sOut   = regionB;                   // [2 sh][4 t][256 d]

    const int tid  = threadIdx.x;
    const int b    = blockIdx.x >> 7;
    const int t0   = (blockIdx.x & 127) * 4;
    const int w    = tid >> 6;
    const int lane = tid & 63;

    // ---- e2 / vc into registers (wave-uniform addresses; L1 broadcast) ----
    float4 e2r[4][4];
    float4 vcr[4];
    #pragma unroll
    for (int j = 0; j < 4; ++j) {
        const int hq = w * 4 + j;
        const float4 vv = *(const float4*)&vc[hq * 4];
        vcr[j] = make_float4(-2.f*vv.x, -2.f*vv.y, -2.f*vv.z, -2.f*vv.w);
        #pragma unroll
        for (int t = 0; t < 4; ++t)
            e2r[t][j] = *(const float4*)&e2g[(b*SEQ + t0 + t)*HDIM + hq*4];
    }

    // ---- prefetch e1 chunk 0 ----
    float4 pf[4];
    #pragma unroll
    for (int j = 0; j < 4; ++j) {
        const int i = tid + j*512;
        const int hq = i & 31, sl = i >> 5;
        pf[j] = *(const float4*)&e1g[(b*SEQ + sl)*HDIM + hq*4];
    }

    // ---- score phase ----
    for (int c = 0; c < 8; ++c) {
        __syncthreads();
        // write staged e1 (swizzled) + reduce previous chunk's partials
        #pragma unroll
        for (int j = 0; j < 4; ++j) {
            const int i = tid + j*512;
            const int hq = i & 31, sl = i >> 5;
            sE1q[hq*64 + (sl ^ (hq & 31))] = pf[j];
        }
        if (c > 0 && tid < 256) {
            const int t = tid >> 6, s = tid & 63;
            float r = 0.f;
            #pragma unroll
            for (int ww = 0; ww < 8; ++ww) r += sPartC[ww*256 + t*64 + s];
            sScore[t*512 + (c-1)*64 + s] = r;
        }
        __syncthreads();
        if (c < 7) {
            #pragma unroll
            for (int j = 0; j < 4; ++j) {
                const int i = tid + j*512;
                const int hq = i & 31, sl = i >> 5;
                pf[j] = *(const float4*)&e1g[(b*SEQ + (c+1)*64 + sl)*HDIM + hq*4];
            }
        }
        float acc[4] = {0.f, 0.f, 0.f, 0.f};
        #pragma unroll
        for (int j = 0; j < 4; ++j) {
            const int hq = w*4 + j;
            const float4 e1 = sE1q[hq*64 + (lane ^ (hq & 31))];
            const float4 a  = vcr[j];
            #pragma unroll
            for (int t = 0; t < 4; ++t) {
                const float4 e2 = e2r[t][j];
                const float f1 = fmaf(e1.x, e2.x, 1.f);
                const float f2 = fmaf(e1.y, e2.y, 1.f);
                const float f3 = fmaf(e1.z, e2.z, 1.f);
                const float f4 = fmaf(e1.w, e2.w, 1.f);
                const float f12 = f1 * f2, f34 = f3 * f4;
                const float n12 = fmaf(a.x, f2, a.y * f1);
                const float n34 = fmaf(a.z, f4, a.w * f3);
                const float num = fmaf(n12, f34, n34 * f12);
                acc[t] = fmaf(num, __builtin_amdgcn_rcpf(f12 * f34), acc[t]);
            }
        }
        #pragma unroll
        for (int t = 0; t < 4; ++t)
            sPartC[w*256 + t*64 + lane] = acc[t];
    }
    __syncthreads();
    if (tid < 256) {   // reduce final chunk
        const int t = tid >> 6, s = tid & 63;
        float r = 0.f;
        #pragma unroll
        for (int ww = 0; ww < 8; ++ww) r += sPartC[ww*256 + t*64 + s];
        sScore[t*512 + 7*64 + s] = r;
    }
    __syncthreads();

    // ---- softmax (waves 0..3, t = w) ----
    float v[8];
    float inv = 0.f;
    if (w < 4) {
        float m = -1e30f;
        #pragma unroll
        for (int j = 0; j < 8; ++j) {
            v[j] = sScore[w*512 + lane + j*64];
            m = fmaxf(m, v[j]);
        }
        #pragma unroll
        for (int off = 32; off; off >>= 1) m = fmaxf(m, __shfl_xor(m, off));
        float sum = 0.f;
        #pragma unroll
        for (int j = 0; j < 8; ++j) {
            v[j] = __builtin_amdgcn_exp2f((v[j] - m) * LOG2E);
            sum += v[j];
        }
        #pragma unroll
        for (int off = 32; off; off >>= 1) sum += __shfl_xor(sum, off);
        inv = __builtin_amdgcn_rcpf(sum);
    }
    __syncthreads();           // all sScore reads done
    if (w < 4) {
        #pragma unroll
        for (int j = 0; j < 8; ++j)
            sPn[(lane + j*64)*4 + w] = v[j] * inv;
    }

    // ---- P@x ----
    const int dq = w & 3, sh = w >> 2;
    const int d  = dq*64 + lane;
    float o0 = 0.f, o1 = 0.f, o2 = 0.f, o3 = 0.f;
    for (int cc = 0; cc < 8; ++cc) {
        __syncthreads();       // sPn written (cc=0); Xs free
        #pragma unroll
        for (int j = 0; j < 8; ++j) {
            const int i = tid + j*512;
            const int s = i >> 6, d4 = (i & 63)*4;
            *(float4*)&Xs[s*256 + d4] =
                *(const float4*)&x[(b*SEQ + cc*64 + s)*DDIM + d4];
        }
        __syncthreads();
        #pragma unroll 8
        for (int si = 0; si < 32; ++si) {
            const int s = sh*32 + si;
            const float4 p  = *(const float4*)&sPn[(cc*64 + s)*4];
            const float  xv = Xs[s*256 + d];
            o0 = fmaf(p.x, xv, o0);
            o1 = fmaf(p.y, xv, o1);
            o2 = fmaf(p.z, xv, o2);
            o3 = fmaf(p.w, xv, o3);
        }
    }
    __syncthreads();           // all sPn reads done
    sOut[(sh*4 + 0)*256 + d] = o0;
    sOut[(sh*4 + 1)*256 + d] = o1;
    sOut[(sh*4 + 2)*256 + d] = o2;
    sOut[(sh*4 + 3)*256 + d] = o3;
    __syncthreads();
    {
        const int t = tid >> 7, d2 = (tid & 127)*2;
        const float2 p0 = *(const float2*)&sOut[(0*4 + t)*256 + d2];
        const float2 p1 = *(const float2*)&sOut[(1*4 + t)*256 + d2];
        *(float2*)&out[(b*SEQ + t0 + t)*DDIM + d2] =
            make_float2(p0.x + p1.x, p0.y + p1.y);
    }
}

extern "C" void kernel_launch(void* const* d_in, const int* in_sizes, int n_in,
                              void* d_out, int out_size, void* d_ws, size_t ws_size,
                              hipStream_t stream) {
    const float* x   = (const float*)d_in[0];   // (4,512,256)
    const float* y   = (const float*)d_in[1];   // (4,512,256)
    const float* W1  = (const float*)d_in[2];   // (128,256)
    const float* W2  = (const float*)d_in[3];   // (128,256)
    const float* vc  = (const float*)d_in[4];   // (1,128)
    float* outp = (float*)d_out;                // (4,512,256)

    float* ws = (float*)d_ws;
    float* e1 = ws;                             // 4*512*128
    float* e2 = ws + NB * SEQ * HDIM;           // 4*512*128

    hipLaunchKernelGGL(proj_kernel, dim3(512), dim3(256), 0, stream,
                       x, y, W1, W2, e1, e2);
    hipLaunchKernelGGL(attn_kernel, dim3(512), dim3(512), 0, stream,
                       e1, e2, vc, x, outp);
}

// Round 4
// 122.906 us; speedup vs baseline: 1.1134x; 1.1134x over previous
//
#include <hip/hip_runtime.h>

// B=4, Sx=Sy=512, H=128, D=2H=256, fp32.
// e1 = exp2(2log2e * x@W1^T), e2 = exp2(2log2e * y@W2^T)
// tanh(s1+s2) = 1 - 2/(e1*e2+1); score = sum_h vc[h]*tanh(.)
// constant sum_h vc[h] dropped (softmax shift-invariant); the -2 factor is
// folded into the cross-wave partial reduction.
// P = softmax_s(score); out = P @ x.
// Quad-rcp: v1/f1+v2/f2+v3/f4+v4/f4 = (n12*f34+n34*f12)/(f12*f34).

#define NB 4
#define SEQ 512
#define HDIM 128
#define DDIM 256

static constexpr float TWO_LOG2E = 2.8853900817779268f; // 2*log2(e)
static constexpr float LOG2E     = 1.4426950408889634f;

// ---------------- Kernel A1: partial projections ---------------------------
// 1024 blocks x 256 thr. Block = (k-half kq, 8 rows of the 4096 virtual rows).
// Thread = (hq=tid&31, ks=tid>>5): 4h x 8r x 16k register block. A-tile in
// LDS (broadcast reads), W from L2 (each line reused 4x in-thread). In-block
// k-reduce over ks via LDS, partial written to ws.
__global__ __launch_bounds__(256) void proj_part_kernel(
    const float* __restrict__ x, const float* __restrict__ y,
    const float* __restrict__ W1, const float* __restrict__ W2,
    float* __restrict__ part)
{
    __shared__ float As[1024];      // [8 r][128 k]
    __shared__ float sPr[8192];     // [8 ks][8 r][128 h]
    const int tid = threadIdx.x;
    const int blk = blockIdx.x;           // [0,1024)
    const int kq  = blk >> 9;             // k-half
    const int gr0 = (blk & 511) * 8;      // global row base [0,4096)

    const float* in; const float* W; int srow;
    if (gr0 < 2048) { in = x; W = W1; srow = gr0; }
    else            { in = y; W = W2; srow = gr0 - 2048; }

    {
        const int r = tid >> 5, kk = tid & 31;
        *(float4*)&As[tid * 4] =
            *(const float4*)&in[(srow + r) * 256 + kq * 128 + kk * 4];
    }
    __syncthreads();

    const int hq = tid & 31;
    const int ks = tid >> 5;

    float4 acc4[8];
    #pragma unroll
    for (int r = 0; r < 8; ++r) acc4[r] = make_float4(0.f, 0.f, 0.f, 0.f);

    #pragma unroll
    for (int u = 0; u < 4; ++u) {
        const int kof = kq * 128 + ks * 16 + u * 4;
        const float4 w0 = *(const float4*)&W[(4*hq + 0) * 256 + kof];
        const float4 w1 = *(const float4*)&W[(4*hq + 1) * 256 + kof];
        const float4 w2 = *(const float4*)&W[(4*hq + 2) * 256 + kof];
        const float4 w3 = *(const float4*)&W[(4*hq + 3) * 256 + kof];
        #pragma unroll
        for (int r = 0; r < 8; ++r) {
            const float4 a = *(const float4*)&As[r * 128 + ks * 16 + u * 4];
            acc4[r].x = fmaf(a.w,w0.w, fmaf(a.z,w0.z, fmaf(a.y,w0.y, fmaf(a.x,w0.x, acc4[r].x))));
            acc4[r].y = fmaf(a.w,w1.w, fmaf(a.z,w1.z, fmaf(a.y,w1.y, fmaf(a.x,w1.x, acc4[r].y))));
            acc4[r].z = fmaf(a.w,w2.w, fmaf(a.z,w2.z, fmaf(a.y,w2.y, fmaf(a.x,w2.x, acc4[r].z))));
            acc4[r].w = fmaf(a.w,w3.w, fmaf(a.z,w3.z, fmaf(a.y,w3.y, fmaf(a.x,w3.x, acc4[r].w))));
        }
    }
    #pragma unroll
    for (int r = 0; r < 8; ++r)
        *(float4*)&sPr[ks * 1024 + r * 128 + hq * 4] = acc4[r];
    __syncthreads();
    {
        const int r = tid >> 5, h4 = (tid & 31) * 4;
        float4 s = make_float4(0.f, 0.f, 0.f, 0.f);
        #pragma unroll
        for (int k2 = 0; k2 < 8; ++k2) {
            const float4 p = *(const float4*)&sPr[k2 * 1024 + r * 128 + h4];
            s.x += p.x; s.y += p.y; s.z += p.z; s.w += p.w;
        }
        *(float4*)&part[kq * 524288 + (gr0 + r) * 128 + h4] = s;
    }
}

// ---------------- Kernel A2: combine k-halves + exp2 -----------------------
__global__ __launch_bounds__(256) void proj_combine_kernel(
    const float* __restrict__ part,
    float* __restrict__ e1, float* __restrict__ e2)
{
    const int j = blockIdx.x * 256 + threadIdx.x;   // float4 idx [0,131072)
    const float4 p0 = ((const float4*)part)[j];
    const float4 p1 = ((const float4*)part)[j + 131072];
    float4 o;
    o.x = __builtin_amdgcn_exp2f((p0.x + p1.x) * TWO_LOG2E);
    o.y = __builtin_amdgcn_exp2f((p0.y + p1.y) * TWO_LOG2E);
    o.z = __builtin_amdgcn_exp2f((p0.z + p1.z) * TWO_LOG2E);
    o.w = __builtin_amdgcn_exp2f((p0.w + p1.w) * TWO_LOG2E);
    const int gr = j >> 5;
    if (gr < 2048) ((float4*)e1)[j] = o;
    else           ((float4*)e2)[j - 65536] = o;
}

// ---------------- Kernel B: fused scores + softmax + P@x -------------------
// 512 blocks x 512 thr (8 waves). Block = (b, 4 t rows). Wave w owns h-quads
// 4w..4w+3 for ALL 4 t. e2/vc come in through SGPRs (wave-uniform indices via
// readfirstlane -> s_load) — zero VGPR arrays, zero LDS reads for them.
// e1 staged per 64-s chunk, XOR-swizzled (conflict-free both ways). Partials
// reduced across waves in LDS (x -2 folded in). P@x: wave owns 64-s slice,
// lane owns a d-quad, x read straight from global (L2-hot, 2 MB total),
// probs broadcast from LDS; cross-wave combine in regionA.
__global__ __launch_bounds__(512) void attn_kernel(
    const float* __restrict__ e1g, const float* __restrict__ e2g,
    const float* __restrict__ vc,  const float* __restrict__ x,
    float* __restrict__ out)
{
    __shared__ float regionA[8192];   // 32 KB: sE1q (score) / sOut (P@x)
    __shared__ float regionB[2048];   // 8 KB: sScore [4t][512s] / sPn [512s][4t]
    __shared__ float sPartC[2048];    // 8 KB: [8 w][4 t][64 s]

    float4* sE1q = (float4*)regionA;  // [32 hq][64 s] swizzled
    float*  sScore = regionB;

    const int tid  = threadIdx.x;
    const int b    = blockIdx.x >> 7;
    const int t0   = (blockIdx.x & 127) * 4;
    const int w    = tid >> 6;
    const int lane = tid & 63;
    const int wu   = __builtin_amdgcn_readfirstlane(w);

    // ---- scalar operands: e2 rows + vc quads for this wave's 16 h --------
    float4 e2s[4][4];
    float4 vcs[4];
    #pragma unroll
    for (int j = 0; j < 4; ++j) {
        vcs[j] = *(const float4*)&vc[(wu * 4 + j) * 4];
        #pragma unroll
        for (int t = 0; t < 4; ++t)
            e2s[t][j] = *(const float4*)&e2g[(b * SEQ + t0 + t) * HDIM + (wu * 4 + j) * 4];
    }

    // ---- prefetch e1 chunk 0 ----
    float4 pf[4];
    #pragma unroll
    for (int j = 0; j < 4; ++j) {
        const int i = tid + j * 512;
        const int hq = i & 31, sl = i >> 5;
        pf[j] = *(const float4*)&e1g[(b * SEQ + sl) * HDIM + hq * 4];
    }

    // ---- score phase ----
    for (int c = 0; c < 8; ++c) {
        __syncthreads();
        #pragma unroll
        for (int j = 0; j < 4; ++j) {
            const int i = tid + j * 512;
            const int hq = i & 31, sl = i >> 5;
            sE1q[hq * 64 + (sl ^ hq)] = pf[j];
        }
        if (c > 0 && tid < 256) {
            const int t = tid >> 6, s = tid & 63;
            float r = 0.f;
            #pragma unroll
            for (int ww = 0; ww < 8; ++ww) r += sPartC[ww * 256 + t * 64 + s];
            sScore[t * 512 + (c - 1) * 64 + s] = -2.f * r;
        }
        __syncthreads();
        if (c < 7) {
            #pragma unroll
            for (int j = 0; j < 4; ++j) {
                const int i = tid + j * 512;
                const int hq = i & 31, sl = i >> 5;
                pf[j] = *(const float4*)&e1g[(b * SEQ + (c + 1) * 64 + sl) * HDIM + hq * 4];
            }
        }
        float acc[4] = {0.f, 0.f, 0.f, 0.f};
        #pragma unroll
        for (int j = 0; j < 4; ++j) {
            const int hq = wu * 4 + j;
            const float4 e1 = sE1q[hq * 64 + (lane ^ hq)];
            const float4 vv = vcs[j];
            #pragma unroll
            for (int t = 0; t < 4; ++t) {
                const float4 e2 = e2s[t][j];
                const float f1 = fmaf(e1.x, e2.x, 1.f);
                const float f2 = fmaf(e1.y, e2.y, 1.f);
                const float f3 = fmaf(e1.z, e2.z, 1.f);
                const float f4 = fmaf(e1.w, e2.w, 1.f);
                const float f12 = f1 * f2, f34 = f3 * f4;
                const float n12 = fmaf(vv.x, f2, vv.y * f1);
                const float n34 = fmaf(vv.z, f4, vv.w * f3);
                const float num = fmaf(n12, f34, n34 * f12);
                acc[t] = fmaf(num, __builtin_amdgcn_rcpf(f12 * f34), acc[t]);
            }
        }
        #pragma unroll
        for (int t = 0; t < 4; ++t)
            sPartC[w * 256 + t * 64 + lane] = acc[t];
    }
    __syncthreads();
    if (tid < 256) {
        const int t = tid >> 6, s = tid & 63;
        float r = 0.f;
        #pragma unroll
        for (int ww = 0; ww < 8; ++ww) r += sPartC[ww * 256 + t * 64 + s];
        sScore[t * 512 + 7 * 64 + s] = -2.f * r;
    }
    __syncthreads();

    // ---- softmax (waves 0..3, t = w) ----
    float v[8];
    float inv = 0.f;
    if (w < 4) {
        float m = -1e30f;
        #pragma unroll
        for (int j = 0; j < 8; ++j) {
            v[j] = sScore[w * 512 + lane + j * 64];
            m = fmaxf(m, v[j]);
        }
        #pragma unroll
        for (int off = 32; off; off >>= 1) m = fmaxf(m, __shfl_xor(m, off));
        float sum = 0.f;
        #pragma unroll
        for (int j = 0; j < 8; ++j) {
            v[j] = __builtin_amdgcn_exp2f((v[j] - m) * LOG2E);
            sum += v[j];
        }
        #pragma unroll
        for (int off = 32; off; off >>= 1) sum += __shfl_xor(sum, off);
        inv = __builtin_amdgcn_rcpf(sum);
    }
    __syncthreads();            // all sScore reads done before sPn overwrite
    if (w < 4) {
        #pragma unroll
        for (int j = 0; j < 8; ++j)
            regionB[(lane + j * 64) * 4 + w] = v[j] * inv;   // sPn[s][t]
    }
    __syncthreads();            // sPn visible

    // ---- P@x: wave owns s in [wu*64, wu*64+64), lane owns d-quad ----
    const float4* x4  = (const float4*)x;
    const float4* pn4 = (const float4*)regionB;   // [512 s] of 4 probs
    float4 po[4];
    #pragma unroll
    for (int t = 0; t < 4; ++t) po[t] = make_float4(0.f, 0.f, 0.f, 0.f);
    #pragma unroll 4
    for (int si = 0; si < 64; ++si) {
        const int s = wu * 64 + si;
        const float4 p  = pn4[s];
        const float4 xv = x4[(b * SEQ + s) * 64 + lane];
        po[0].x = fmaf(p.x, xv.x, po[0].x); po[0].y = fmaf(p.x, xv.y, po[0].y);
        po[0].z = fmaf(p.x, xv.z, po[0].z); po[0].w = fmaf(p.x, xv.w, po[0].w);
        po[1].x = fmaf(p.y, xv.x, po[1].x); po[1].y = fmaf(p.y, xv.y, po[1].y);
        po[1].z = fmaf(p.y, xv.z, po[1].z); po[1].w = fmaf(p.y, xv.w, po[1].w);
        po[2].x = fmaf(p.z, xv.x, po[2].x); po[2].y = fmaf(p.z, xv.y, po[2].y);
        po[2].z = fmaf(p.z, xv.z, po[2].z); po[2].w = fmaf(p.z, xv.w, po[2].w);
        po[3].x = fmaf(p.w, xv.x, po[3].x); po[3].y = fmaf(p.w, xv.y, po[3].y);
        po[3].z = fmaf(p.w, xv.z, po[3].z); po[3].w = fmaf(p.w, xv.w, po[3].w);
    }
    float4* sOut4 = (float4*)regionA;             // [8 w][4 t][64 dq]
    #pragma unroll
    for (int t = 0; t < 4; ++t)
        sOut4[w * 256 + t * 64 + lane] = po[t];
    __syncthreads();
    {
        const int i = tid * 2;                    // [0,1024) elems: 4t x 256d
        const int t = i >> 8, d = i & 255;
        float2 ssum = make_float2(0.f, 0.f);
        #pragma unroll
        for (int ww = 0; ww < 8; ++ww) {
            const float2 pv = *(const float2*)&regionA[ww * 1024 + t * 256 + d];
            ssum.x += pv.x; ssum.y += pv.y;
        }
        *(float2*)&out[(b * SEQ + t0 + t) * DDIM + d] = ssum;
    }
}

extern "C" void kernel_launch(void* const* d_in, const int* in_sizes, int n_in,
                              void* d_out, int out_size, void* d_ws, size_t ws_size,
                              hipStream_t stream) {
    const float* x   = (const float*)d_in[0];   // (4,512,256)
    const float* y   = (const float*)d_in[1];   // (4,512,256)
    const float* W1  = (const float*)d_in[2];   // (128,256)
    const float* W2  = (const float*)d_in[3];   // (128,256)
    const float* vc  = (const float*)d_in[4];   // (1,128)
    float* outp = (float*)d_out;                // (4,512,256)

    float* ws   = (float*)d_ws;
    float* e1   = ws;                           // 4*512*128   = 1 MB
    float* e2   = ws + NB * SEQ * HDIM;         // 1 MB
    float* part = ws + 2 * NB * SEQ * HDIM;     // 2*4096*128  = 4 MB

    hipLaunchKernelGGL(proj_part_kernel,    dim3(1024), dim3(256), 0, stream,
                       x, y, W1, W2, part);
    hipLaunchKernelGGL(proj_combine_kernel, dim3(512),  dim3(256), 0, stream,
                       part, e1, e2);
    hipLaunchKernelGGL(attn_kernel,         dim3(512),  dim3(512), 0, stream,
                       e1, e2, vc, x, outp);
}